// Round 6
// baseline (1152.583 us; speedup 1.0000x reference)
//
#include <hip/hip_runtime.h>
#include <math.h>

#define N_NODES 100000
#define N_EDGES 1600000
#define IN_C 512
#define HID_C 128
#define OUT_C 64
#define N_LAYERS 8

typedef short bf16x8 __attribute__((ext_vector_type(8)));
typedef float f32x4 __attribute__((ext_vector_type(4)));

static __device__ __forceinline__ ushort f2bf(float f) {
  uint u = __float_as_uint(f);
  u = (u + 0x7FFFu + ((u >> 16) & 1u)) >> 16;
  return (ushort)u;
}
static __device__ __forceinline__ float bflo(uint u) { return __uint_as_float(u << 16); }
static __device__ __forceinline__ float bfhi(uint u) { return __uint_as_float(u & 0xffff0000u); }

// ---------------------------------------------------------------------------
// CSR build
// ---------------------------------------------------------------------------
__global__ __launch_bounds__(256) void hist_kernel(const int* __restrict__ dst,
                                                   int* __restrict__ cnt) {
  int e = blockIdx.x * 256 + threadIdx.x;
  atomicAdd(&cnt[dst[e]], 1);
}

__global__ __launch_bounds__(256) void scan_block(const int* __restrict__ in,
                                                  int* __restrict__ out,
                                                  int* __restrict__ bsum, int n) {
  __shared__ int tsum[256];
  int t = threadIdx.x;
  int base = blockIdx.x * 1024 + t * 4;
  int v0 = (base + 0 < n) ? in[base + 0] : 0;
  int v1 = (base + 1 < n) ? in[base + 1] : 0;
  int v2 = (base + 2 < n) ? in[base + 2] : 0;
  int v3 = (base + 3 < n) ? in[base + 3] : 0;
  int s = v0 + v1 + v2 + v3;
  tsum[t] = s;
  __syncthreads();
  for (int off = 1; off < 256; off <<= 1) {
    int x = (t >= off) ? tsum[t - off] : 0;
    __syncthreads();
    tsum[t] += x;
    __syncthreads();
  }
  int excl = tsum[t] - s;
  int i0 = excl + v0, i1 = i0 + v1, i2 = i1 + v2, i3 = i2 + v3;
  if (base + 0 < n) out[base + 0] = i0;
  if (base + 1 < n) out[base + 1] = i1;
  if (base + 2 < n) out[base + 2] = i2;
  if (base + 3 < n) out[base + 3] = i3;
  if (t == 255 && bsum) bsum[blockIdx.x] = tsum[255];
}

__global__ __launch_bounds__(256) void finalize_rows(const int* __restrict__ incl,
                                                     const int* __restrict__ auxi,
                                                     int* __restrict__ row, int n) {
  int i = blockIdx.x * 256 + threadIdx.x;
  if (i < n) {
    int g = i >> 10;
    int off = g ? auxi[g - 1] : 0;
    row[i + 1] = incl[i] + off;
    if (i == 0) row[0] = 0;
  }
}

__global__ __launch_bounds__(256) void init_cursor(const int* __restrict__ row,
                                                   int* __restrict__ cur, int n) {
  int i = blockIdx.x * 256 + threadIdx.x;
  if (i < n) cur[i] = row[i];
}

// pack (weight ~bf16 rounded : 15 bits) << 17 | (src : 17 bits) into 4 bytes
__global__ __launch_bounds__(256) void fill_csr(const int* __restrict__ src,
                                                const int* __restrict__ dst,
                                                const float* __restrict__ w,
                                                int* __restrict__ cur,
                                                uint* __restrict__ epk) {
  int e = blockIdx.x * 256 + threadIdx.x;
  int d = dst[e];
  int p = atomicAdd(&cur[d], 1);
  uint fb = __float_as_uint(w[e]) + 0x8000u;  // round-to-nearest into top 15 bits
  epk[p] = ((fb >> 16) << 17) | (uint)src[e];
}

// ---------------------------------------------------------------------------
// Pre-cast weights fp32 -> bf16 (W_convs transposed per layer)
// ---------------------------------------------------------------------------
__global__ __launch_bounds__(256) void cast_weights(const float* __restrict__ we,
                                                    const float* __restrict__ wc,
                                                    const float* __restrict__ wd,
                                                    ushort* __restrict__ web,
                                                    ushort* __restrict__ wcb,
                                                    ushort* __restrict__ wdb) {
  int i = blockIdx.x * 256 + threadIdx.x;
  if (i < 128 * 512) web[i] = f2bf(we[i]);
  if (i < 8 * 128 * 128) {
    int layer = i >> 14, rem = i & 16383, k = rem >> 7, j = rem & 127;
    wcb[(layer << 14) + (j << 7) + k] = f2bf(wc[i]);  // wcb[l][j][k] = W[l][k][j]
  }
  if (i < 64 * 128) wdb[i] = f2bf(wd[i]);
}

// ---------------------------------------------------------------------------
// Encoder MFMA: h = x @ W_enc.T  x:[N,512]fp32, W:[128,512]bf16 -> h:[N,128]bf16
// ---------------------------------------------------------------------------
__global__ __launch_bounds__(256) void enc_mfma(const float* __restrict__ x,
                                                const ushort* __restrict__ wb,
                                                ushort* __restrict__ h) {
  __shared__ ushort xs[32][136];
  __shared__ ushort ws[128][136];
  int tid = threadIdx.x;
  size_t row0 = (size_t)blockIdx.x * 32;
  int lane = tid & 63;
  int wv = tid >> 6;
  int m0 = (wv >> 1) * 16;
  int n0 = (wv & 1) * 64;
  int arow = m0 + (lane & 15);
  int akb = (lane >> 4) * 8;
  f32x4 acc[4] = {};
  for (int kc = 0; kc < 4; kc++) {
    int k0 = kc * 128;
    __syncthreads();
#pragma unroll
    for (int i = 0; i < 4; i++) {
      int u = tid + i * 256;
      int r = u >> 5, c4 = u & 31;
      float4 v = *(const float4*)(x + (row0 + r) * IN_C + k0 + c4 * 4);
      uint2 p;
      p.x = (uint)f2bf(v.x) | ((uint)f2bf(v.y) << 16);
      p.y = (uint)f2bf(v.z) | ((uint)f2bf(v.w) << 16);
      *(uint2*)&xs[r][c4 * 4] = p;
    }
#pragma unroll
    for (int i = 0; i < 8; i++) {
      int u = tid + i * 256;
      int c = u >> 4, o = u & 15;
      *(uint4*)&ws[c][o * 8] = *(const uint4*)(wb + (size_t)c * IN_C + k0 + o * 8);
    }
    __syncthreads();
#pragma unroll
    for (int ks = 0; ks < 4; ks++) {
      int kk = ks * 32 + akb;
      bf16x8 a = *(bf16x8*)&xs[arow][kk];
#pragma unroll
      for (int n = 0; n < 4; n++) {
        bf16x8 b = *(bf16x8*)&ws[n0 + n * 16 + (lane & 15)][kk];
        acc[n] = __builtin_amdgcn_mfma_f32_16x16x32_bf16(a, b, acc[n], 0, 0, 0);
      }
    }
  }
  int crow = m0 + (lane >> 4) * 4;
  int ccol = lane & 15;
#pragma unroll
  for (int n = 0; n < 4; n++)
#pragma unroll
    for (int r = 0; r < 4; r++)
      h[(row0 + crow + r) * HID_C + n0 + n * 16 + ccol] = f2bf(acc[n][r]);
}

// ---------------------------------------------------------------------------
// Fused aggregation + conv:
//   hh[n] = 0.9*sum_e w_e*h[src_e] + 0.1*x0[n]      (gather, reg accum)
//   h_out[n] = relu((1-b)*hh + b*(hh @ W))          (LDS tile + MFMA)
// Block = 32 nodes; wave w owns nodes [b*32+w*8, +8), lane = 2 channels.
// Gather issues 8 row-loads in flight (masked tail batch: w=0, src=0).
// ---------------------------------------------------------------------------
__global__ __launch_bounds__(256) void agg_conv(const ushort* __restrict__ h,
                                                const ushort* __restrict__ x0,
                                                const int* __restrict__ row,
                                                const uint* __restrict__ epk,
                                                const ushort* __restrict__ wb,
                                                ushort* __restrict__ out,
                                                float onemb, float beta) {
  __shared__ ushort hs[32][136];
  __shared__ ushort ws[128][136];
  int tid = threadIdx.x;
  int lane = tid & 63;
  int wv = tid >> 6;
  int node0 = blockIdx.x * 32;

  // stage W^T tile (consumed after the barrier)
#pragma unroll
  for (int i = 0; i < 8; i++) {
    int u = tid + i * 256;
    int c = u >> 4, o = u & 15;
    *(uint4*)&ws[c][o * 8] = *(const uint4*)(wb + (size_t)c * HID_C + o * 8);
  }

  const uint* hp = (const uint*)h + lane;  // h row = 64 uints
  for (int i = 0; i < 8; i++) {
    int node = node0 + wv * 8 + i;
    int beg = row[node], end = row[node + 1];
    float a0 = 0.f, a1 = 0.f;
    for (int e = beg; e < end; e += 8) {
      uint p0 = (e + 0 < end) ? epk[e + 0] : 0u;
      uint p1 = (e + 1 < end) ? epk[e + 1] : 0u;
      uint p2 = (e + 2 < end) ? epk[e + 2] : 0u;
      uint p3 = (e + 3 < end) ? epk[e + 3] : 0u;
      uint p4 = (e + 4 < end) ? epk[e + 4] : 0u;
      uint p5 = (e + 5 < end) ? epk[e + 5] : 0u;
      uint p6 = (e + 6 < end) ? epk[e + 6] : 0u;
      uint p7 = (e + 7 < end) ? epk[e + 7] : 0u;
      uint h0 = hp[(size_t)(p0 & 0x1FFFFu) * 64];
      uint h1 = hp[(size_t)(p1 & 0x1FFFFu) * 64];
      uint h2 = hp[(size_t)(p2 & 0x1FFFFu) * 64];
      uint h3 = hp[(size_t)(p3 & 0x1FFFFu) * 64];
      uint h4 = hp[(size_t)(p4 & 0x1FFFFu) * 64];
      uint h5 = hp[(size_t)(p5 & 0x1FFFFu) * 64];
      uint h6 = hp[(size_t)(p6 & 0x1FFFFu) * 64];
      uint h7 = hp[(size_t)(p7 & 0x1FFFFu) * 64];
      float w0 = __uint_as_float((p0 >> 17) << 16);
      float w1 = __uint_as_float((p1 >> 17) << 16);
      float w2 = __uint_as_float((p2 >> 17) << 16);
      float w3 = __uint_as_float((p3 >> 17) << 16);
      float w4 = __uint_as_float((p4 >> 17) << 16);
      float w5 = __uint_as_float((p5 >> 17) << 16);
      float w6 = __uint_as_float((p6 >> 17) << 16);
      float w7 = __uint_as_float((p7 >> 17) << 16);
      a0 = fmaf(w0, bflo(h0), a0); a1 = fmaf(w0, bfhi(h0), a1);
      a0 = fmaf(w1, bflo(h1), a0); a1 = fmaf(w1, bfhi(h1), a1);
      a0 = fmaf(w2, bflo(h2), a0); a1 = fmaf(w2, bfhi(h2), a1);
      a0 = fmaf(w3, bflo(h3), a0); a1 = fmaf(w3, bfhi(h3), a1);
      a0 = fmaf(w4, bflo(h4), a0); a1 = fmaf(w4, bfhi(h4), a1);
      a0 = fmaf(w5, bflo(h5), a0); a1 = fmaf(w5, bfhi(h5), a1);
      a0 = fmaf(w6, bflo(h6), a0); a1 = fmaf(w6, bfhi(h6), a1);
      a0 = fmaf(w7, bflo(h7), a0); a1 = fmaf(w7, bfhi(h7), a1);
    }
    uint xv = ((const uint*)x0)[(size_t)node * 64 + lane];
    float o0 = 0.9f * a0 + 0.1f * bflo(xv);
    float o1 = 0.9f * a1 + 0.1f * bfhi(xv);
    ((uint*)&hs[wv * 8 + i][0])[lane] = (uint)f2bf(o0) | ((uint)f2bf(o1) << 16);
  }
  __syncthreads();

  // conv on the 32-row LDS tile
  int m0 = (wv >> 1) * 16, n0 = (wv & 1) * 64;
  int arow = m0 + (lane & 15), akb = (lane >> 4) * 8;
  f32x4 acc[4] = {};
#pragma unroll
  for (int ks = 0; ks < 4; ks++) {
    int kk = ks * 32 + akb;
    bf16x8 a = *(bf16x8*)&hs[arow][kk];
#pragma unroll
    for (int n = 0; n < 4; n++) {
      bf16x8 b = *(bf16x8*)&ws[n0 + n * 16 + (lane & 15)][kk];
      acc[n] = __builtin_amdgcn_mfma_f32_16x16x32_bf16(a, b, acc[n], 0, 0, 0);
    }
  }
  int crow = m0 + (lane >> 4) * 4, ccol = lane & 15;
#pragma unroll
  for (int n = 0; n < 4; n++)
#pragma unroll
    for (int r = 0; r < 4; r++) {
      float hv = bflo((uint)hs[crow + r][n0 + n * 16 + ccol]);
      float o = fmaxf(onemb * hv + beta * acc[n][r], 0.f);
      out[(size_t)(node0 + crow + r) * HID_C + n0 + n * 16 + ccol] = f2bf(o);
    }
}

// ---------------------------------------------------------------------------
// Decoder MFMA: out = h @ W_dec.T -> fp32 [N,64]
// ---------------------------------------------------------------------------
__global__ __launch_bounds__(256) void dec_mfma(const ushort* __restrict__ h,
                                                const ushort* __restrict__ wb,
                                                float* __restrict__ out) {
  __shared__ ushort hs[32][136];
  __shared__ ushort ws[64][136];
  int tid = threadIdx.x;
  size_t row0 = (size_t)blockIdx.x * 32;
  {
    int r = tid >> 3, o = tid & 7;
    *(uint4*)&hs[r][o * 16] = *(const uint4*)(h + (row0 + r) * HID_C + o * 16);
    *(uint4*)&hs[r][o * 16 + 8] = *(const uint4*)(h + (row0 + r) * HID_C + o * 16 + 8);
  }
#pragma unroll
  for (int i = 0; i < 4; i++) {
    int u = tid + i * 256;
    int c = u >> 4, o = u & 15;
    *(uint4*)&ws[c][o * 8] = *(const uint4*)(wb + (size_t)c * HID_C + o * 8);
  }
  __syncthreads();
  int lane = tid & 63, wv = tid >> 6;
  int m0 = (wv >> 1) * 16, n0 = (wv & 1) * 32;
  int arow = m0 + (lane & 15), akb = (lane >> 4) * 8;
  f32x4 acc[2] = {};
#pragma unroll
  for (int ks = 0; ks < 4; ks++) {
    int kk = ks * 32 + akb;
    bf16x8 a = *(bf16x8*)&hs[arow][kk];
#pragma unroll
    for (int n = 0; n < 2; n++) {
      bf16x8 b = *(bf16x8*)&ws[n0 + n * 16 + (lane & 15)][kk];
      acc[n] = __builtin_amdgcn_mfma_f32_16x16x32_bf16(a, b, acc[n], 0, 0, 0);
    }
  }
  int crow = m0 + (lane >> 4) * 4, ccol = lane & 15;
#pragma unroll
  for (int n = 0; n < 2; n++)
#pragma unroll
    for (int r = 0; r < 4; r++)
      out[(row0 + crow + r) * OUT_C + n0 + n * 16 + ccol] = acc[n][r];
}

// ---------------------------------------------------------------------------
extern "C" void kernel_launch(void* const* d_in, const int* in_sizes, int n_in,
                              void* d_out, int out_size, void* d_ws, size_t ws_size,
                              hipStream_t stream) {
  const float* x = (const float*)d_in[0];
  const int* ei = (const int*)d_in[1];
  const float* ew = (const float*)d_in[2];
  const float* Wenc = (const float*)d_in[3];
  const float* Wconvs = (const float*)d_in[4];
  const float* Wdec = (const float*)d_in[5];
  float* out = (float*)d_out;

  char* p = (char*)d_ws;
  ushort* H0 = (ushort*)p; p += (size_t)N_NODES * HID_C * 2;
  ushort* HA = (ushort*)p; p += (size_t)N_NODES * HID_C * 2;
  ushort* HB = (ushort*)p; p += (size_t)N_NODES * HID_C * 2;
  uint* EPK = (uint*)p;    p += (size_t)N_EDGES * 4;
  ushort* WENC = (ushort*)p;  p += 128 * 512 * 2;
  ushort* WCONV = (ushort*)p; p += 8 * 128 * 128 * 2;
  ushort* WDEC = (ushort*)p;  p += 64 * 128 * 2;
  int* ROW = (int*)p;  p += (N_NODES + 1) * 4;
  int* CNT = (int*)p;  p += N_NODES * 4;
  int* INCL = (int*)p; p += N_NODES * 4;
  int* CUR = (int*)p;  p += N_NODES * 4;
  int* AUX = (int*)p;  p += 128 * 4;
  int* AUXI = (int*)p;

  const int* src = ei;
  const int* dst = ei + N_EDGES;

  // weights -> bf16 (W_convs transposed per layer)
  cast_weights<<<512, 256, 0, stream>>>(Wenc, Wconvs, Wdec, WENC, WCONV, WDEC);

  // CSR build
  hipMemsetAsync(CNT, 0, N_NODES * sizeof(int), stream);
  hist_kernel<<<N_EDGES / 256, 256, 0, stream>>>(dst, CNT);
  scan_block<<<98, 256, 0, stream>>>(CNT, INCL, AUX, N_NODES);
  scan_block<<<1, 256, 0, stream>>>(AUX, AUXI, nullptr, 98);
  finalize_rows<<<391, 256, 0, stream>>>(INCL, AUXI, ROW, N_NODES);
  init_cursor<<<391, 256, 0, stream>>>(ROW, CUR, N_NODES);
  fill_csr<<<N_EDGES / 256, 256, 0, stream>>>(src, dst, ew, CUR, EPK);

  // encoder
  enc_mfma<<<3125, 256, 0, stream>>>(x, WENC, H0);

  // layers (fused aggregation + conv)
  const ushort* cur = H0;
  ushort* bufs[2] = {HA, HB};
  for (int i = 0; i < N_LAYERS; i++) {
    ushort* nxt = bufs[i & 1];
    float beta = logf(0.5f / (float)(i + 1) + 1.0f);
    agg_conv<<<3125, 256, 0, stream>>>(cur, H0, ROW, EPK,
                                       WCONV + (size_t)i * HID_C * HID_C, nxt,
                                       1.0f - beta, beta);
    cur = nxt;
  }

  // decoder
  dec_mfma<<<3125, 256, 0, stream>>>(cur, WDEC, out);
}

// Round 7
// 835.130 us; speedup vs baseline: 1.3801x; 1.3801x over previous
//
#include <hip/hip_runtime.h>
#include <math.h>

#define N_NODES 100000
#define N_EDGES 1600000
#define IN_C 512
#define HID_C 128
#define OUT_C 64
#define N_LAYERS 8

typedef short bf16x8 __attribute__((ext_vector_type(8)));
typedef float f32x4 __attribute__((ext_vector_type(4)));

static __device__ __forceinline__ ushort f2bf(float f) {
  uint u = __float_as_uint(f);
  u = (u + 0x7FFFu + ((u >> 16) & 1u)) >> 16;
  return (ushort)u;
}
static __device__ __forceinline__ float bflo(uint u) { return __uint_as_float(u << 16); }
static __device__ __forceinline__ float bfhi(uint u) { return __uint_as_float(u & 0xffff0000u); }

// ---------------------------------------------------------------------------
// CSR build
// ---------------------------------------------------------------------------
__global__ __launch_bounds__(256) void hist_kernel(const int* __restrict__ dst,
                                                   int* __restrict__ cnt) {
  int e = blockIdx.x * 256 + threadIdx.x;
  atomicAdd(&cnt[dst[e]], 1);
}

__global__ __launch_bounds__(256) void scan_block(const int* __restrict__ in,
                                                  int* __restrict__ out,
                                                  int* __restrict__ bsum, int n) {
  __shared__ int tsum[256];
  int t = threadIdx.x;
  int base = blockIdx.x * 1024 + t * 4;
  int v0 = (base + 0 < n) ? in[base + 0] : 0;
  int v1 = (base + 1 < n) ? in[base + 1] : 0;
  int v2 = (base + 2 < n) ? in[base + 2] : 0;
  int v3 = (base + 3 < n) ? in[base + 3] : 0;
  int s = v0 + v1 + v2 + v3;
  tsum[t] = s;
  __syncthreads();
  for (int off = 1; off < 256; off <<= 1) {
    int x = (t >= off) ? tsum[t - off] : 0;
    __syncthreads();
    tsum[t] += x;
    __syncthreads();
  }
  int excl = tsum[t] - s;
  int i0 = excl + v0, i1 = i0 + v1, i2 = i1 + v2, i3 = i2 + v3;
  if (base + 0 < n) out[base + 0] = i0;
  if (base + 1 < n) out[base + 1] = i1;
  if (base + 2 < n) out[base + 2] = i2;
  if (base + 3 < n) out[base + 3] = i3;
  if (t == 255 && bsum) bsum[blockIdx.x] = tsum[255];
}

__global__ __launch_bounds__(256) void finalize_rows(const int* __restrict__ incl,
                                                     const int* __restrict__ auxi,
                                                     int* __restrict__ row, int n) {
  int i = blockIdx.x * 256 + threadIdx.x;
  if (i < n) {
    int g = i >> 10;
    int off = g ? auxi[g - 1] : 0;
    row[i + 1] = incl[i] + off;
    if (i == 0) row[0] = 0;
  }
}

__global__ __launch_bounds__(256) void init_cursor(const int* __restrict__ row,
                                                   int* __restrict__ cur, int n) {
  int i = blockIdx.x * 256 + threadIdx.x;
  if (i < n) cur[i] = row[i];
}

// pack (weight ~bf16 rounded : 15 bits) << 17 | (src : 17 bits) into 4 bytes
__global__ __launch_bounds__(256) void fill_csr(const int* __restrict__ src,
                                                const int* __restrict__ dst,
                                                const float* __restrict__ w,
                                                int* __restrict__ cur,
                                                uint* __restrict__ epk) {
  int e = blockIdx.x * 256 + threadIdx.x;
  int d = dst[e];
  int p = atomicAdd(&cur[d], 1);
  uint fb = __float_as_uint(w[e]) + 0x8000u;  // round-to-nearest into top 15 bits
  epk[p] = ((fb >> 16) << 17) | (uint)src[e];
}

// ---------------------------------------------------------------------------
// Pre-cast weights fp32 -> bf16 (W_convs transposed per layer)
// ---------------------------------------------------------------------------
__global__ __launch_bounds__(256) void cast_weights(const float* __restrict__ we,
                                                    const float* __restrict__ wc,
                                                    const float* __restrict__ wd,
                                                    ushort* __restrict__ web,
                                                    ushort* __restrict__ wcb,
                                                    ushort* __restrict__ wdb) {
  int i = blockIdx.x * 256 + threadIdx.x;
  if (i < 128 * 512) web[i] = f2bf(we[i]);
  if (i < 8 * 128 * 128) {
    int layer = i >> 14, rem = i & 16383, k = rem >> 7, j = rem & 127;
    wcb[(layer << 14) + (j << 7) + k] = f2bf(wc[i]);  // wcb[l][j][k] = W[l][k][j]
  }
  if (i < 64 * 128) wdb[i] = f2bf(wd[i]);
}

// ---------------------------------------------------------------------------
// Encoder MFMA: h = x @ W_enc.T  x:[N,512]fp32, W:[128,512]bf16 -> h:[N,128]bf16
// ---------------------------------------------------------------------------
__global__ __launch_bounds__(256) void enc_mfma(const float* __restrict__ x,
                                                const ushort* __restrict__ wb,
                                                ushort* __restrict__ h) {
  __shared__ ushort xs[32][136];
  __shared__ ushort ws[128][136];
  int tid = threadIdx.x;
  size_t row0 = (size_t)blockIdx.x * 32;
  int lane = tid & 63;
  int wv = tid >> 6;
  int m0 = (wv >> 1) * 16;
  int n0 = (wv & 1) * 64;
  int arow = m0 + (lane & 15);
  int akb = (lane >> 4) * 8;
  f32x4 acc[4] = {};
  for (int kc = 0; kc < 4; kc++) {
    int k0 = kc * 128;
    __syncthreads();
#pragma unroll
    for (int i = 0; i < 4; i++) {
      int u = tid + i * 256;
      int r = u >> 5, c4 = u & 31;
      float4 v = *(const float4*)(x + (row0 + r) * IN_C + k0 + c4 * 4);
      uint2 p;
      p.x = (uint)f2bf(v.x) | ((uint)f2bf(v.y) << 16);
      p.y = (uint)f2bf(v.z) | ((uint)f2bf(v.w) << 16);
      *(uint2*)&xs[r][c4 * 4] = p;
    }
#pragma unroll
    for (int i = 0; i < 8; i++) {
      int u = tid + i * 256;
      int c = u >> 4, o = u & 15;
      *(uint4*)&ws[c][o * 8] = *(const uint4*)(wb + (size_t)c * IN_C + k0 + o * 8);
    }
    __syncthreads();
#pragma unroll
    for (int ks = 0; ks < 4; ks++) {
      int kk = ks * 32 + akb;
      bf16x8 a = *(bf16x8*)&xs[arow][kk];
#pragma unroll
      for (int n = 0; n < 4; n++) {
        bf16x8 b = *(bf16x8*)&ws[n0 + n * 16 + (lane & 15)][kk];
        acc[n] = __builtin_amdgcn_mfma_f32_16x16x32_bf16(a, b, acc[n], 0, 0, 0);
      }
    }
  }
  int crow = m0 + (lane >> 4) * 4;
  int ccol = lane & 15;
#pragma unroll
  for (int n = 0; n < 4; n++)
#pragma unroll
    for (int r = 0; r < 4; r++)
      h[(row0 + crow + r) * HID_C + n0 + n * 16 + ccol] = f2bf(acc[n][r]);
}

// ---------------------------------------------------------------------------
// Aggregation: hh[n] = 0.9*sum w_e*h[src_e] + 0.1*x0[n]
// One wave per node, lane = 2 channels. Masked 8-deep batches (MLP=8):
// invalid slot -> p=0 -> w=0.0, gathers hot row 0 (harmless).
// ---------------------------------------------------------------------------
__global__ __launch_bounds__(256) void agg_bf(const ushort* __restrict__ h,
                                              const ushort* __restrict__ x0,
                                              const int* __restrict__ row,
                                              const uint* __restrict__ epk,
                                              ushort* __restrict__ out) {
  int node = (blockIdx.x * 256 + threadIdx.x) >> 6;
  int lane = threadIdx.x & 63;
  int beg = row[node], end = row[node + 1];
  float a0 = 0.f, a1 = 0.f;
  const uint* hp = (const uint*)h + lane;  // h row = 64 uints
  for (int e = beg; e < end; e += 8) {
    uint p0 = (e + 0 < end) ? epk[e + 0] : 0u;
    uint p1 = (e + 1 < end) ? epk[e + 1] : 0u;
    uint p2 = (e + 2 < end) ? epk[e + 2] : 0u;
    uint p3 = (e + 3 < end) ? epk[e + 3] : 0u;
    uint p4 = (e + 4 < end) ? epk[e + 4] : 0u;
    uint p5 = (e + 5 < end) ? epk[e + 5] : 0u;
    uint p6 = (e + 6 < end) ? epk[e + 6] : 0u;
    uint p7 = (e + 7 < end) ? epk[e + 7] : 0u;
    uint h0 = hp[(size_t)(p0 & 0x1FFFFu) * 64];
    uint h1 = hp[(size_t)(p1 & 0x1FFFFu) * 64];
    uint h2 = hp[(size_t)(p2 & 0x1FFFFu) * 64];
    uint h3 = hp[(size_t)(p3 & 0x1FFFFu) * 64];
    uint h4 = hp[(size_t)(p4 & 0x1FFFFu) * 64];
    uint h5 = hp[(size_t)(p5 & 0x1FFFFu) * 64];
    uint h6 = hp[(size_t)(p6 & 0x1FFFFu) * 64];
    uint h7 = hp[(size_t)(p7 & 0x1FFFFu) * 64];
    float w0 = __uint_as_float((p0 >> 17) << 16);
    float w1 = __uint_as_float((p1 >> 17) << 16);
    float w2 = __uint_as_float((p2 >> 17) << 16);
    float w3 = __uint_as_float((p3 >> 17) << 16);
    float w4 = __uint_as_float((p4 >> 17) << 16);
    float w5 = __uint_as_float((p5 >> 17) << 16);
    float w6 = __uint_as_float((p6 >> 17) << 16);
    float w7 = __uint_as_float((p7 >> 17) << 16);
    a0 = fmaf(w0, bflo(h0), a0); a1 = fmaf(w0, bfhi(h0), a1);
    a0 = fmaf(w1, bflo(h1), a0); a1 = fmaf(w1, bfhi(h1), a1);
    a0 = fmaf(w2, bflo(h2), a0); a1 = fmaf(w2, bfhi(h2), a1);
    a0 = fmaf(w3, bflo(h3), a0); a1 = fmaf(w3, bfhi(h3), a1);
    a0 = fmaf(w4, bflo(h4), a0); a1 = fmaf(w4, bfhi(h4), a1);
    a0 = fmaf(w5, bflo(h5), a0); a1 = fmaf(w5, bfhi(h5), a1);
    a0 = fmaf(w6, bflo(h6), a0); a1 = fmaf(w6, bfhi(h6), a1);
    a0 = fmaf(w7, bflo(h7), a0); a1 = fmaf(w7, bfhi(h7), a1);
  }
  uint xv = ((const uint*)x0)[(size_t)node * 64 + lane];
  float o0 = 0.9f * a0 + 0.1f * bflo(xv);
  float o1 = 0.9f * a1 + 0.1f * bfhi(xv);
  ((uint*)out)[(size_t)node * 64 + lane] = (uint)f2bf(o0) | ((uint)f2bf(o1) << 16);
}

// ---------------------------------------------------------------------------
// Conv MFMA (in-place): h = relu((1-b)*hh + b*(hh @ W)); wb is W^T per layer
// ---------------------------------------------------------------------------
__global__ __launch_bounds__(256) void conv_mfma(ushort* __restrict__ hbuf,
                                                 const ushort* __restrict__ wb,
                                                 float onemb, float beta) {
  __shared__ ushort hs[32][136];
  __shared__ ushort ws[128][136];
  int tid = threadIdx.x;
  size_t row0 = (size_t)blockIdx.x * 32;
  {
    int r = tid >> 3, o = tid & 7;
    *(uint4*)&hs[r][o * 16] = *(const uint4*)(hbuf + (row0 + r) * HID_C + o * 16);
    *(uint4*)&hs[r][o * 16 + 8] = *(const uint4*)(hbuf + (row0 + r) * HID_C + o * 16 + 8);
  }
#pragma unroll
  for (int i = 0; i < 8; i++) {
    int u = tid + i * 256;
    int c = u >> 4, o = u & 15;
    *(uint4*)&ws[c][o * 8] = *(const uint4*)(wb + (size_t)c * HID_C + o * 8);
  }
  __syncthreads();
  int lane = tid & 63;
  int wv = tid >> 6;
  int m0 = (wv >> 1) * 16, n0 = (wv & 1) * 64;
  int arow = m0 + (lane & 15), akb = (lane >> 4) * 8;
  f32x4 acc[4] = {};
#pragma unroll
  for (int ks = 0; ks < 4; ks++) {
    int kk = ks * 32 + akb;
    bf16x8 a = *(bf16x8*)&hs[arow][kk];
#pragma unroll
    for (int n = 0; n < 4; n++) {
      bf16x8 b = *(bf16x8*)&ws[n0 + n * 16 + (lane & 15)][kk];
      acc[n] = __builtin_amdgcn_mfma_f32_16x16x32_bf16(a, b, acc[n], 0, 0, 0);
    }
  }
  __syncthreads();
  int crow = m0 + (lane >> 4) * 4, ccol = lane & 15;
#pragma unroll
  for (int n = 0; n < 4; n++)
#pragma unroll
    for (int r = 0; r < 4; r++) {
      float hv = bflo((uint)hs[crow + r][n0 + n * 16 + ccol]);
      float o = fmaxf(onemb * hv + beta * acc[n][r], 0.f);
      hbuf[(row0 + crow + r) * HID_C + n0 + n * 16 + ccol] = f2bf(o);
    }
}

// ---------------------------------------------------------------------------
// Decoder MFMA: out = h @ W_dec.T -> fp32 [N,64]
// ---------------------------------------------------------------------------
__global__ __launch_bounds__(256) void dec_mfma(const ushort* __restrict__ h,
                                                const ushort* __restrict__ wb,
                                                float* __restrict__ out) {
  __shared__ ushort hs[32][136];
  __shared__ ushort ws[64][136];
  int tid = threadIdx.x;
  size_t row0 = (size_t)blockIdx.x * 32;
  {
    int r = tid >> 3, o = tid & 7;
    *(uint4*)&hs[r][o * 16] = *(const uint4*)(h + (row0 + r) * HID_C + o * 16);
    *(uint4*)&hs[r][o * 16 + 8] = *(const uint4*)(h + (row0 + r) * HID_C + o * 16 + 8);
  }
#pragma unroll
  for (int i = 0; i < 4; i++) {
    int u = tid + i * 256;
    int c = u >> 4, o = u & 15;
    *(uint4*)&ws[c][o * 8] = *(const uint4*)(wb + (size_t)c * HID_C + o * 8);
  }
  __syncthreads();
  int lane = tid & 63, wv = tid >> 6;
  int m0 = (wv >> 1) * 16, n0 = (wv & 1) * 32;
  int arow = m0 + (lane & 15), akb = (lane >> 4) * 8;
  f32x4 acc[2] = {};
#pragma unroll
  for (int ks = 0; ks < 4; ks++) {
    int kk = ks * 32 + akb;
    bf16x8 a = *(bf16x8*)&hs[arow][kk];
#pragma unroll
    for (int n = 0; n < 2; n++) {
      bf16x8 b = *(bf16x8*)&ws[n0 + n * 16 + (lane & 15)][kk];
      acc[n] = __builtin_amdgcn_mfma_f32_16x16x32_bf16(a, b, acc[n], 0, 0, 0);
    }
  }
  int crow = m0 + (lane >> 4) * 4, ccol = lane & 15;
#pragma unroll
  for (int n = 0; n < 2; n++)
#pragma unroll
    for (int r = 0; r < 4; r++)
      out[(row0 + crow + r) * OUT_C + n0 + n * 16 + ccol] = acc[n][r];
}

// ---------------------------------------------------------------------------
extern "C" void kernel_launch(void* const* d_in, const int* in_sizes, int n_in,
                              void* d_out, int out_size, void* d_ws, size_t ws_size,
                              hipStream_t stream) {
  const float* x = (const float*)d_in[0];
  const int* ei = (const int*)d_in[1];
  const float* ew = (const float*)d_in[2];
  const float* Wenc = (const float*)d_in[3];
  const float* Wconvs = (const float*)d_in[4];
  const float* Wdec = (const float*)d_in[5];
  float* out = (float*)d_out;

  char* p = (char*)d_ws;
  ushort* H0 = (ushort*)p; p += (size_t)N_NODES * HID_C * 2;
  ushort* HA = (ushort*)p; p += (size_t)N_NODES * HID_C * 2;
  ushort* HB = (ushort*)p; p += (size_t)N_NODES * HID_C * 2;
  uint* EPK = (uint*)p;    p += (size_t)N_EDGES * 4;
  ushort* WENC = (ushort*)p;  p += 128 * 512 * 2;
  ushort* WCONV = (ushort*)p; p += 8 * 128 * 128 * 2;
  ushort* WDEC = (ushort*)p;  p += 64 * 128 * 2;
  int* ROW = (int*)p;  p += (N_NODES + 1) * 4;
  int* CNT = (int*)p;  p += N_NODES * 4;
  int* INCL = (int*)p; p += N_NODES * 4;
  int* CUR = (int*)p;  p += N_NODES * 4;
  int* AUX = (int*)p;  p += 128 * 4;
  int* AUXI = (int*)p;

  const int* src = ei;
  const int* dst = ei + N_EDGES;

  // weights -> bf16 (W_convs transposed per layer)
  cast_weights<<<512, 256, 0, stream>>>(Wenc, Wconvs, Wdec, WENC, WCONV, WDEC);

  // CSR build
  hipMemsetAsync(CNT, 0, N_NODES * sizeof(int), stream);
  hist_kernel<<<N_EDGES / 256, 256, 0, stream>>>(dst, CNT);
  scan_block<<<98, 256, 0, stream>>>(CNT, INCL, AUX, N_NODES);
  scan_block<<<1, 256, 0, stream>>>(AUX, AUXI, nullptr, 98);
  finalize_rows<<<391, 256, 0, stream>>>(INCL, AUXI, ROW, N_NODES);
  init_cursor<<<391, 256, 0, stream>>>(ROW, CUR, N_NODES);
  fill_csr<<<N_EDGES / 256, 256, 0, stream>>>(src, dst, ew, CUR, EPK);

  // encoder
  enc_mfma<<<3125, 256, 0, stream>>>(x, WENC, H0);

  // layers
  const ushort* cur = H0;
  ushort* bufs[2] = {HA, HB};
  for (int i = 0; i < N_LAYERS; i++) {
    ushort* nxt = bufs[i & 1];
    agg_bf<<<25000, 256, 0, stream>>>(cur, H0, ROW, EPK, nxt);
    float beta = logf(0.5f / (float)(i + 1) + 1.0f);
    conv_mfma<<<3125, 256, 0, stream>>>(nxt, WCONV + (size_t)i * HID_C * HID_C,
                                        1.0f - beta, beta);
    cur = nxt;
  }

  // decoder
  dec_mfma<<<3125, 256, 0, stream>>>(cur, WDEC, out);
}